// Round 3
// baseline (3318.372 us; speedup 1.0000x reference)
//
#include <hip/hip_runtime.h>
#include <cstddef>

// Problem constants (fixed by setup_inputs): B=8, C=512, N=4096, M=1024.
// Inputs: float32. Output: float32. Internal staging: bf16 (threshold is bf16-floor).
#define Bn 8
#define Cd 512
#define Nn 4096
#define Mm 1024

__device__ __forceinline__ float b2f(unsigned short u) {
    union { unsigned int i; float f; } v; v.i = ((unsigned int)u) << 16; return v.f;
}
__device__ __forceinline__ unsigned short f2b(float f) {
    union { float f; unsigned int i; } v; v.f = f;
    unsigned int x = v.i;
    unsigned int r = (x + 0x7FFFu + ((x >> 16) & 1u)) >> 16;  // RNE
    return (unsigned short)r;
}
__device__ __forceinline__ float u2lo(unsigned int u) {
    union { unsigned int i; float f; } v; v.i = u << 16; return v.f;
}
__device__ __forceinline__ float u2hi(unsigned int u) {
    union { unsigned int i; float f; } v; v.i = u & 0xFFFF0000u; return v.f;
}

// ---------------------------------------------------------------------------
// Stage 1: Y = W (512x512) @ X (512xNx), per batch b. f32 inputs.
// MODE 0: store f32,  Y[o*Nx + n]        (skip -> d_out)
// MODE 2: store bf16, Y[n*512 + o]       (K^T, V^T -> ws)
// 64x64 tile, 256 threads, 4x4 microtile, K-tile 16.
// ---------------------------------------------------------------------------
template <int MODE>
__global__ __launch_bounds__(256) void gemm512(const float* __restrict__ W,
                                               const float* __restrict__ X,
                                               float* __restrict__ Yf,
                                               unsigned short* __restrict__ Yb,
                                               int Nx) {
    __shared__ float Ws[16][65];
    __shared__ float Xs[16][65];
    const int t = threadIdx.x;
    const int b = blockIdx.z;
    const int o0 = blockIdx.y * 64;
    const int n0 = blockIdx.x * 64;
    const float* Xb = X + (size_t)b * Cd * Nx;

    float acc[4][4];
#pragma unroll
    for (int i = 0; i < 4; ++i)
#pragma unroll
        for (int j = 0; j < 4; ++j) acc[i][j] = 0.f;

    const int ty = t >> 4, tx = t & 15;

    for (int k0 = 0; k0 < Cd; k0 += 16) {
        {   // W tile: Ws[k][o]
            int o = t >> 2;
            int k4 = (t & 3) * 4;
            float4 w = *(const float4*)(W + (size_t)(o0 + o) * Cd + k0 + k4);
            Ws[k4 + 0][o] = w.x; Ws[k4 + 1][o] = w.y;
            Ws[k4 + 2][o] = w.z; Ws[k4 + 3][o] = w.w;
        }
        {   // X tile: Xs[k][n]
            int k = t >> 4;
            int n4 = (t & 15) * 4;
            float4 x = *(const float4*)(Xb + (size_t)(k0 + k) * Nx + n0 + n4);
            Xs[k][n4 + 0] = x.x; Xs[k][n4 + 1] = x.y;
            Xs[k][n4 + 2] = x.z; Xs[k][n4 + 3] = x.w;
        }
        __syncthreads();
#pragma unroll
        for (int k = 0; k < 16; ++k) {
            float a0 = Ws[k][ty * 4 + 0], a1 = Ws[k][ty * 4 + 1];
            float a2 = Ws[k][ty * 4 + 2], a3 = Ws[k][ty * 4 + 3];
            float b0 = Xs[k][tx * 4 + 0], b1 = Xs[k][tx * 4 + 1];
            float b2 = Xs[k][tx * 4 + 2], b3 = Xs[k][tx * 4 + 3];
            acc[0][0] += a0 * b0; acc[0][1] += a0 * b1; acc[0][2] += a0 * b2; acc[0][3] += a0 * b3;
            acc[1][0] += a1 * b0; acc[1][1] += a1 * b1; acc[1][2] += a1 * b2; acc[1][3] += a1 * b3;
            acc[2][0] += a2 * b0; acc[2][1] += a2 * b1; acc[2][2] += a2 * b2; acc[2][3] += a2 * b3;
            acc[3][0] += a3 * b0; acc[3][1] += a3 * b1; acc[3][2] += a3 * b2; acc[3][3] += a3 * b3;
        }
        __syncthreads();
    }

#pragma unroll
    for (int i = 0; i < 4; ++i) {
#pragma unroll
        for (int j = 0; j < 4; ++j) {
            int o = o0 + ty * 4 + i;
            int n = n0 + tx * 4 + j;
            if (MODE == 0) {
                Yf[(size_t)b * Cd * Nx + (size_t)o * Nx + n] = acc[i][j];
            } else {
                Yb[(size_t)b * Nx * Cd + (size_t)n * Cd + o] = f2b(acc[i][j]);
            }
        }
    }
}

// ---------------------------------------------------------------------------
// Stage 2: fused Q-GEMM + flash attention.
// Block = 256 threads handles (b, 16 query rows n0..n0+15).
// Prologue computes q = Wq @ up-slice in-block (Q never hits global).
// Main loop: online softmax over M in chunks of 64; K^T/V^T read as bf16.
// LDS: Qs f32 (33KB) + union{ prologue Us 16KB + Wt 8KB | Ps+state 4.4KB }
//      = 57.6 KB static, 2 blocks/CU.
// ---------------------------------------------------------------------------
__global__ __launch_bounds__(256) void attn_k(const float* __restrict__ up,
                                              const float* __restrict__ Wq,
                                              const unsigned short* __restrict__ Ktb,
                                              const unsigned short* __restrict__ Vtb,
                                              float* __restrict__ out) {
    __shared__ float Qs[16][516];   // pitch 516: 16B-aligned rows, bank-shifted
    __shared__ __align__(16) unsigned char Sraw[24576];
    // prologue view (bf16 staging)
    unsigned short (*Us)[16]  = reinterpret_cast<unsigned short(*)[16]>(Sraw);           // 16384 B
    unsigned short (*Wt)[512] = reinterpret_cast<unsigned short(*)[512]>(Sraw + 16384);  //  8192 B
    // main-loop view (aliases prologue region; guarded by syncs)
    float (*Ps)[65] = reinterpret_cast<float(*)[65]>(Sraw);    // 4160 B
    float* mu_s     = reinterpret_cast<float*>(Sraw + 4160);
    float* ssum_s   = reinterpret_cast<float*>(Sraw + 4224);
    float* alpha_s  = reinterpret_cast<float*>(Sraw + 4288);

    const int t = threadIdx.x;
    const int b = blockIdx.y;
    const int n0 = blockIdx.x * 16;
    const int row = t & 15;
    const int grp = t >> 4;

    // ---- stage up-slice (f32 -> bf16): Us[c][r] = up[b][c][n0+r] ----
    for (int i = t; i < Cd * 16; i += 256) {
        int c = i >> 4, r = i & 15;
        Us[c][r] = f2b(up[((size_t)b * Cd + c) * Nn + n0 + r]);
    }
    __syncthreads();

    // ---- Q-GEMM prologue: acc[j] = q[grp*32+j][n0+row] ----
    float acc[32];
#pragma unroll
    for (int j = 0; j < 32; ++j) acc[j] = 0.f;

    for (int k0 = 0; k0 < Cd; k0 += 8) {
        // stage Wt[k][oc] = bf16(Wq[oc][k0+k]) for k in [0,8)
        for (int i = t; i < 1024; i += 256) {
            int oc = i >> 1;
            int kc = (i & 1) * 4;
            float4 w = *(const float4*)(Wq + (size_t)oc * Cd + k0 + kc);
            Wt[kc + 0][oc] = f2b(w.x); Wt[kc + 1][oc] = f2b(w.y);
            Wt[kc + 2][oc] = f2b(w.z); Wt[kc + 3][oc] = f2b(w.w);
        }
        __syncthreads();
#pragma unroll
        for (int k = 0; k < 8; ++k) {
            float u = b2f(Us[k0 + k][row]);
            const ushort4* wr = (const ushort4*)(&Wt[k][grp * 32]);
#pragma unroll
            for (int j4 = 0; j4 < 8; ++j4) {
                ushort4 w = wr[j4];
                acc[j4 * 4 + 0] += u * b2f(w.x);
                acc[j4 * 4 + 1] += u * b2f(w.y);
                acc[j4 * 4 + 2] += u * b2f(w.z);
                acc[j4 * 4 + 3] += u * b2f(w.w);
            }
        }
        __syncthreads();   // protects Wt for next stage AND Us before union reuse
    }

    // write pre-scaled q to Qs; init softmax state; reset acc as O accumulator
    const float scale = 0.04419417382415922f;  // 1/sqrt(512)
#pragma unroll
    for (int j = 0; j < 32; ++j) Qs[row][grp * 32 + j] = acc[j] * scale;
    if (t < 16) { mu_s[t] = -1e30f; ssum_s[t] = 0.f; }
#pragma unroll
    for (int j = 0; j < 32; ++j) acc[j] = 0.f;
    __syncthreads();

    const float4* qr = (const float4*)(&Qs[row][0]);

    for (int m0 = 0; m0 < Mm; m0 += 64) {
        // ---- Phase A: S chunk [16 rows][64 m], 4 dots per thread ----
        {
            int mb = m0 + grp * 4;
            const uint4* K0 = (const uint4*)(Ktb + ((size_t)b * Mm + mb + 0) * Cd);
            const uint4* K1 = (const uint4*)(Ktb + ((size_t)b * Mm + mb + 1) * Cd);
            const uint4* K2 = (const uint4*)(Ktb + ((size_t)b * Mm + mb + 2) * Cd);
            const uint4* K3 = (const uint4*)(Ktb + ((size_t)b * Mm + mb + 3) * Cd);
            float a0 = 0.f, a1 = 0.f, a2 = 0.f, a3 = 0.f;
#pragma unroll 4
            for (int c8 = 0; c8 < Cd / 8; ++c8) {
                float4 qa = qr[2 * c8], qb = qr[2 * c8 + 1];
                uint4 k0v = K0[c8], k1v = K1[c8], k2v = K2[c8], k3v = K3[c8];
                a0 += qa.x * u2lo(k0v.x) + qa.y * u2hi(k0v.x) + qa.z * u2lo(k0v.y) + qa.w * u2hi(k0v.y)
                    + qb.x * u2lo(k0v.z) + qb.y * u2hi(k0v.z) + qb.z * u2lo(k0v.w) + qb.w * u2hi(k0v.w);
                a1 += qa.x * u2lo(k1v.x) + qa.y * u2hi(k1v.x) + qa.z * u2lo(k1v.y) + qa.w * u2hi(k1v.y)
                    + qb.x * u2lo(k1v.z) + qb.y * u2hi(k1v.z) + qb.z * u2lo(k1v.w) + qb.w * u2hi(k1v.w);
                a2 += qa.x * u2lo(k2v.x) + qa.y * u2hi(k2v.x) + qa.z * u2lo(k2v.y) + qa.w * u2hi(k2v.y)
                    + qb.x * u2lo(k2v.z) + qb.y * u2hi(k2v.z) + qb.z * u2lo(k2v.w) + qb.w * u2hi(k2v.w);
                a3 += qa.x * u2lo(k3v.x) + qa.y * u2hi(k3v.x) + qa.z * u2lo(k3v.y) + qa.w * u2hi(k3v.y)
                    + qb.x * u2lo(k3v.z) + qb.y * u2hi(k3v.z) + qb.z * u2lo(k3v.w) + qb.w * u2hi(k3v.w);
            }
            Ps[row][grp * 4 + 0] = a0;   // q pre-scaled, no extra scale
            Ps[row][grp * 4 + 1] = a1;
            Ps[row][grp * 4 + 2] = a2;
            Ps[row][grp * 4 + 3] = a3;
        }
        __syncthreads();
        // ---- Phase B: per-row online-softmax update (16 threads) ----
        if (t < 16) {
            float mold = mu_s[t];
            float mx = mold;
            for (int m = 0; m < 64; ++m) mx = fmaxf(mx, Ps[t][m]);
            float al = __expf(mold - mx);
            float s = ssum_s[t] * al;
            for (int m = 0; m < 64; ++m) {
                float p = __expf(Ps[t][m] - mx);
                Ps[t][m] = p;
                s += p;
            }
            mu_s[t] = mx; ssum_s[t] = s; alpha_s[t] = al;
        }
        __syncthreads();
        // ---- Phase C: O = O*alpha + P @ V^T chunk ----
        {
            float ar = alpha_s[row];
#pragma unroll
            for (int j = 0; j < 32; ++j) acc[j] *= ar;
            const unsigned short* Vbase = Vtb + (size_t)b * Mm * Cd + (size_t)grp * 32;
            for (int m = 0; m < 64; ++m) {
                float p = Ps[row][m];
                const uint4* vr = (const uint4*)(Vbase + (size_t)(m0 + m) * Cd);
#pragma unroll
                for (int j4 = 0; j4 < 4; ++j4) {
                    uint4 v = vr[j4];
                    acc[j4 * 8 + 0] += p * u2lo(v.x); acc[j4 * 8 + 1] += p * u2hi(v.x);
                    acc[j4 * 8 + 2] += p * u2lo(v.y); acc[j4 * 8 + 3] += p * u2hi(v.y);
                    acc[j4 * 8 + 4] += p * u2lo(v.z); acc[j4 * 8 + 5] += p * u2hi(v.z);
                    acc[j4 * 8 + 6] += p * u2lo(v.w); acc[j4 * 8 + 7] += p * u2hi(v.w);
                }
            }
        }
        __syncthreads();
    }

    float inv = 1.0f / ssum_s[row];
#pragma unroll
    for (int j = 0; j < 32; ++j) {
        int c = grp * 32 + j;
        size_t idx = ((size_t)b * Cd + c) * Nn + n0 + row;
        out[idx] = out[idx] + acc[j] * inv;
    }
}

// ---------------------------------------------------------------------------
extern "C" void kernel_launch(void* const* d_in, const int* in_sizes, int n_in,
                              void* d_out, int out_size, void* d_ws, size_t ws_size,
                              hipStream_t stream) {
    const float* up   = (const float*)d_in[0];  // [B,C,N] f32
    const float* down = (const float*)d_in[1];  // [B,C,M] f32
    const float* Wq   = (const float*)d_in[2];  // [C,C]
    const float* Wk   = (const float*)d_in[3];
    const float* Wv   = (const float*)d_in[4];
    const float* Wsk  = (const float*)d_in[5];
    float* out = (float*)d_out;

    // Workspace: K^T bf16 (8 MiB) | V^T bf16 (8 MiB)  -> total 16 MiB
    unsigned short* Ktb = (unsigned short*)d_ws;
    unsigned short* Vtb = Ktb + (size_t)Bn * Mm * Cd;

    gemm512<2><<<dim3(Mm / 64, Cd / 64, Bn), 256, 0, stream>>>(Wk, down, nullptr, Ktb, Mm);
    gemm512<2><<<dim3(Mm / 64, Cd / 64, Bn), 256, 0, stream>>>(Wv, down, nullptr, Vtb, Mm);
    gemm512<0><<<dim3(Nn / 64, Cd / 64, Bn), 256, 0, stream>>>(Wsk, up, out, nullptr, Nn);
    attn_k<<<dim3(Nn / 16, Bn), 256, 0, stream>>>(up, Wq, Ktb, Vtb, out);
}

// Round 4
// 729.845 us; speedup vs baseline: 4.5467x; 4.5467x over previous
//
#include <hip/hip_runtime.h>
#include <cstddef>

// Problem constants: B=8, C=512, N=4096, M=1024. Inputs f32, output f32.
#define Bn 8
#define Cd 512
#define Nn 4096
#define Mm 1024

typedef __attribute__((ext_vector_type(8))) short s8v;
typedef __attribute__((ext_vector_type(4))) float v4f;

__device__ __forceinline__ float b2f(unsigned short u) {
    union { unsigned int i; float f; } v; v.i = ((unsigned int)u) << 16; return v.f;
}
__device__ __forceinline__ unsigned short f2b(float f) {
    union { float f; unsigned int i; } v; v.f = f;
    unsigned int x = v.i;
    unsigned int r = (x + 0x7FFFu + ((x >> 16) & 1u)) >> 16;  // RNE
    return (unsigned short)r;
}
__device__ __forceinline__ v4f mfma16(s8v a, s8v b, v4f c) {
    return __builtin_amdgcn_mfma_f32_16x16x32_bf16(a, b, c, 0, 0, 0);
}

// ---------------------------------------------------------------------------
// MFMA GEMM: D[o][n] = sum_c W[o][c] * X[c][n], per batch. f32 in, bf16 MFMA.
// Tile 64(o) x 64(n), 256 thr / 4 waves; wave w owns o-rows [o0+w*16, +16).
// MODE 0: f32  store D[o][n]   (skip -> out)
// MODE 1: bf16 store D[o][n]   (V -> Vb[c][m])
// MODE 2: bf16 store D^T[n][o] via LDS transpose (Q -> Qt[n][c], K -> Kt[m][c])
// ---------------------------------------------------------------------------
template <int MODE>
__global__ __launch_bounds__(256) void gemm_mfma(const float* __restrict__ W,
                                                 const float* __restrict__ X,
                                                 float* __restrict__ Yf,
                                                 unsigned short* __restrict__ Yb,
                                                 int Nx) {
    __shared__ short Xs[64][40];   // B staging: [n-loc][c-chunk 32] bf16, pad 8
    __shared__ short Tt[16][72];   // MODE 2 transpose staging
    const int t = threadIdx.x;
    const int w = t >> 6, lq = t & 15, quad = (t >> 4) & 3;
    const int b = blockIdx.z, o0 = blockIdx.y * 64, n0 = blockIdx.x * 64;
    const float* Xb = X + (size_t)b * Cd * Nx;
    const float* Wrow = W + (size_t)(o0 + w * 16 + lq) * Cd;

    v4f acc[4];
#pragma unroll
    for (int i = 0; i < 4; ++i) acc[i] = (v4f){0.f, 0.f, 0.f, 0.f};

    for (int c0 = 0; c0 < Cd; c0 += 32) {
        // stage Xs[n][c] bf16 (transpose from X[c][n])
#pragma unroll
        for (int p = 0; p < 2; ++p) {
            int i = t + p * 256;          // 512 float4 slots = 32c x 16(n/4)
            int c = i >> 4;
            int n4 = (i & 15) * 4;
            float4 x = *(const float4*)(Xb + (size_t)(c0 + c) * Nx + n0 + n4);
            Xs[n4 + 0][c] = (short)f2b(x.x); Xs[n4 + 1][c] = (short)f2b(x.y);
            Xs[n4 + 2][c] = (short)f2b(x.z); Xs[n4 + 3][c] = (short)f2b(x.w);
        }
        // A fragment: W[o0+w*16+lq][c0 + quad*8 .. +7], f32 -> bf16
        union { unsigned short h[8]; s8v s; } af;
        {
            float4 wa = *(const float4*)(Wrow + c0 + quad * 8);
            float4 wb = *(const float4*)(Wrow + c0 + quad * 8 + 4);
            af.h[0] = f2b(wa.x); af.h[1] = f2b(wa.y); af.h[2] = f2b(wa.z); af.h[3] = f2b(wa.w);
            af.h[4] = f2b(wb.x); af.h[5] = f2b(wb.y); af.h[6] = f2b(wb.z); af.h[7] = f2b(wb.w);
        }
        __syncthreads();
#pragma unroll
        for (int nt = 0; nt < 4; ++nt) {
            s8v bf = *(const s8v*)(&Xs[nt * 16 + lq][quad * 8]);
            acc[nt] = mfma16(af.s, bf, acc[nt]);
        }
        __syncthreads();
    }

    if (MODE == 0 || MODE == 1) {
#pragma unroll
        for (int nt = 0; nt < 4; ++nt)
#pragma unroll
            for (int r = 0; r < 4; ++r) {
                int o = o0 + w * 16 + quad * 4 + r;
                int n = n0 + nt * 16 + lq;
                size_t idx = ((size_t)b * Cd + o) * Nx + n;
                if (MODE == 0) Yf[idx] = acc[nt][r];
                else           Yb[idx] = f2b(acc[nt][r]);
            }
    } else {
#pragma unroll
        for (int nt = 0; nt < 4; ++nt) {
#pragma unroll
            for (int r = 0; r < 4; ++r)
                Tt[lq][w * 16 + quad * 4 + r] = (short)f2b(acc[nt][r]);
            __syncthreads();
            int nrow = t >> 4, o4 = (t & 15) * 4;
            ushort4 val = *(const ushort4*)(&Tt[nrow][o4]);
            *(ushort4*)(Yb + ((size_t)b * Nx + n0 + nt * 16 + nrow) * Cd + o0 + o4) = val;
            __syncthreads();
        }
    }
}

// ---------------------------------------------------------------------------
// MFMA flash attention: 32 q-rows/block, 4 waves, m-chunks of 64.
// Wave w: row-tile rt=w>>1 (16 rows), m-half mh=w&1 (32 m) for QK^T;
//         column-quarter c0w=w*128 (all 32 rows) for PV.
// Qt[n][c], Kt[m][c], Vb[c][m] all bf16; out += P V / l on top of skip.
// ---------------------------------------------------------------------------
__global__ __launch_bounds__(256) void attn_mfma(const unsigned short* __restrict__ Qt,
                                                 const unsigned short* __restrict__ Kt,
                                                 const unsigned short* __restrict__ Vb,
                                                 float* __restrict__ out) {
    __shared__ short Pb[32][72];          // P bf16, A-layout source
    __shared__ float mu_s[32], ssum_s[32], alpha_s[32];
    __shared__ float pmax[32][2], psum[32][2];
    __shared__ float Ot[64][36];          // epilogue transpose staging

    const int t = threadIdx.x;
    const int w = t >> 6, lq = t & 15, quad = (t >> 4) & 3;
    const int rt = w >> 1, mh = w & 1;
    const int b = blockIdx.y, n0 = blockIdx.x * 32;

    // Q fragments: A[row=rt*16+lq][k], 16 k-blocks of 32
    s8v qa[16];
    {
        const uint4* qp = (const uint4*)(Qt + ((size_t)b * Nn + n0 + rt * 16 + lq) * Cd);
#pragma unroll
        for (int kb = 0; kb < 16; ++kb) {
            union { uint4 u; s8v s; } v; v.u = qp[kb * 4 + quad]; qa[kb] = v.s;
        }
    }
    if (t < 32) { mu_s[t] = -1e30f; ssum_s[t] = 0.f; }

    v4f o_acc[2][8];
#pragma unroll
    for (int i = 0; i < 2; ++i)
#pragma unroll
        for (int j = 0; j < 8; ++j) o_acc[i][j] = (v4f){0.f, 0.f, 0.f, 0.f};
    __syncthreads();

    const uint4* Kb4 = (const uint4*)(Kt + (size_t)b * Mm * Cd);   // row stride 64 uint4
    const uint4* Vb4 = (const uint4*)(Vb + (size_t)b * Cd * Mm);   // row stride 128 uint4

    for (int m0 = 0; m0 < Mm; m0 += 64) {
        // ---- QK^T: 2 m-tiles of 16 for this wave ----
        v4f s0 = (v4f){0.f,0.f,0.f,0.f}, s1 = (v4f){0.f,0.f,0.f,0.f};
        const int mA = m0 + mh * 32 + lq;
        const int mB = mA + 16;
#pragma unroll
        for (int kb = 0; kb < 16; ++kb) {
            union { uint4 u; s8v s; } b0, b1;
            b0.u = Kb4[(size_t)mA * 64 + kb * 4 + quad];
            b1.u = Kb4[(size_t)mB * 64 + kb * 4 + quad];
            s0 = mfma16(qa[kb], b0.s, s0);
            s1 = mfma16(qa[kb], b1.s, s1);
        }
        const float sc = 0.04419417382415922f;  // 1/sqrt(512)
        float m4[4];
#pragma unroll
        for (int r = 0; r < 4; ++r) {
            s0[r] *= sc; s1[r] *= sc;
            m4[r] = fmaxf(s0[r], s1[r]);
        }
#pragma unroll
        for (int d = 1; d < 16; d <<= 1)
#pragma unroll
            for (int r = 0; r < 4; ++r) m4[r] = fmaxf(m4[r], __shfl_xor(m4[r], d));
        if (lq == 0) {
#pragma unroll
            for (int r = 0; r < 4; ++r) pmax[rt * 16 + quad * 4 + r][mh] = m4[r];
        }
        __syncthreads();  // A
        if (t < 32) {
            float mx = fmaxf(mu_s[t], fmaxf(pmax[t][0], pmax[t][1]));
            alpha_s[t] = __expf(mu_s[t] - mx);
            mu_s[t] = mx;
        }
        __syncthreads();  // B
        // ---- exp, P -> LDS (bf16), row partial sums ----
#pragma unroll
        for (int r = 0; r < 4; ++r) {
            int row = rt * 16 + quad * 4 + r;
            float mx = mu_s[row];
            float e0 = __expf(s0[r] - mx), e1 = __expf(s1[r] - mx);
            Pb[row][mh * 32 + lq]      = (short)f2b(e0);
            Pb[row][mh * 32 + 16 + lq] = (short)f2b(e1);
            m4[r] = e0 + e1;
        }
#pragma unroll
        for (int d = 1; d < 16; d <<= 1)
#pragma unroll
            for (int r = 0; r < 4; ++r) m4[r] += __shfl_xor(m4[r], d);
        if (lq == 0) {
#pragma unroll
            for (int r = 0; r < 4; ++r) psum[rt * 16 + quad * 4 + r][mh] = m4[r];
        }
        __syncthreads();  // C
        if (t < 32) ssum_s[t] = ssum_s[t] * alpha_s[t] + psum[t][0] + psum[t][1];

        // ---- PV: wave covers cols [w*128, +128), all 32 rows ----
        s8v pf[2][2];
#pragma unroll
        for (int rtt = 0; rtt < 2; ++rtt)
#pragma unroll
            for (int kb2 = 0; kb2 < 2; ++kb2)
                pf[rtt][kb2] = *(const s8v*)(&Pb[rtt * 16 + lq][kb2 * 32 + quad * 8]);
        float ar[2][4];
#pragma unroll
        for (int rtt = 0; rtt < 2; ++rtt)
#pragma unroll
            for (int r = 0; r < 4; ++r) ar[rtt][r] = alpha_s[rtt * 16 + quad * 4 + r];
#pragma unroll
        for (int rtt = 0; rtt < 2; ++rtt)
#pragma unroll
            for (int ct = 0; ct < 8; ++ct)
#pragma unroll
                for (int r = 0; r < 4; ++r) o_acc[rtt][ct][r] *= ar[rtt][r];
        const int c0w = w * 128;
        const int mbase = m0 >> 3;   // uint4 offset of m0
#pragma unroll
        for (int ct = 0; ct < 8; ++ct) {
#pragma unroll
            for (int kb2 = 0; kb2 < 2; ++kb2) {
                union { uint4 u; s8v s; } vv;
                vv.u = Vb4[(size_t)(c0w + ct * 16 + lq) * 128 + mbase + kb2 * 4 + quad];
                o_acc[0][ct] = mfma16(pf[0][kb2], vv.s, o_acc[0][ct]);
                o_acc[1][ct] = mfma16(pf[1][kb2], vv.s, o_acc[1][ct]);
            }
        }
        // next chunk's syncA orders Pb/pmax reuse
    }

    __syncthreads();
    float inv[2][4];
#pragma unroll
    for (int rtt = 0; rtt < 2; ++rtt)
#pragma unroll
        for (int r = 0; r < 4; ++r) inv[rtt][r] = 1.0f / ssum_s[rtt * 16 + quad * 4 + r];

#pragma unroll
    for (int ct = 0; ct < 8; ++ct) {
#pragma unroll
        for (int rtt = 0; rtt < 2; ++rtt) {
            v4f v = o_acc[rtt][ct];
#pragma unroll
            for (int r = 0; r < 4; ++r) v[r] *= inv[rtt][r];
            *(v4f*)(&Ot[w * 16 + lq][rtt * 16 + quad * 4]) = v;
        }
        __syncthreads();
        int cr = t >> 2, off = (t & 3) * 8;
        int cg = (cr >> 4) * 128 + ct * 16 + (cr & 15);
        float* op = out + ((size_t)b * Cd + cg) * Nn + n0 + off;
        float4 a0 = *(const float4*)(&Ot[cr][off]);
        float4 a1 = *(const float4*)(&Ot[cr][off + 4]);
        float4 g0 = *(const float4*)(op);
        float4 g1 = *(const float4*)(op + 4);
        g0.x += a0.x; g0.y += a0.y; g0.z += a0.z; g0.w += a0.w;
        g1.x += a1.x; g1.y += a1.y; g1.z += a1.z; g1.w += a1.w;
        *(float4*)(op) = g0;
        *(float4*)(op + 4) = g1;
        __syncthreads();
    }
}

// ---------------------------------------------------------------------------
// Fallback VALU attention (round-3 proven) for small ws_size.
// ---------------------------------------------------------------------------
__device__ __forceinline__ float u2lo(unsigned int u) {
    union { unsigned int i; float f; } v; v.i = u << 16; return v.f;
}
__device__ __forceinline__ float u2hi(unsigned int u) {
    union { unsigned int i; float f; } v; v.i = u & 0xFFFF0000u; return v.f;
}

__global__ __launch_bounds__(256) void attn_k(const float* __restrict__ up,
                                              const float* __restrict__ Wq,
                                              const unsigned short* __restrict__ Ktb,
                                              const unsigned short* __restrict__ Vtb,
                                              float* __restrict__ out) {
    __shared__ float Qs[16][516];
    __shared__ __align__(16) unsigned char Sraw[24576];
    unsigned short (*Us)[16]  = reinterpret_cast<unsigned short(*)[16]>(Sraw);
    unsigned short (*Wt)[512] = reinterpret_cast<unsigned short(*)[512]>(Sraw + 16384);
    float (*Ps)[65] = reinterpret_cast<float(*)[65]>(Sraw);
    float* mu_s     = reinterpret_cast<float*>(Sraw + 4160);
    float* ssum_s   = reinterpret_cast<float*>(Sraw + 4224);
    float* alpha_s  = reinterpret_cast<float*>(Sraw + 4288);

    const int t = threadIdx.x;
    const int b = blockIdx.y;
    const int n0 = blockIdx.x * 16;
    const int row = t & 15;
    const int grp = t >> 4;

    for (int i = t; i < Cd * 16; i += 256) {
        int c = i >> 4, r = i & 15;
        Us[c][r] = f2b(up[((size_t)b * Cd + c) * Nn + n0 + r]);
    }
    __syncthreads();

    float acc[32];
#pragma unroll
    for (int j = 0; j < 32; ++j) acc[j] = 0.f;

    for (int k0 = 0; k0 < Cd; k0 += 8) {
        for (int i = t; i < 1024; i += 256) {
            int oc = i >> 1;
            int kc = (i & 1) * 4;
            float4 wv = *(const float4*)(Wq + (size_t)oc * Cd + k0 + kc);
            Wt[kc + 0][oc] = f2b(wv.x); Wt[kc + 1][oc] = f2b(wv.y);
            Wt[kc + 2][oc] = f2b(wv.z); Wt[kc + 3][oc] = f2b(wv.w);
        }
        __syncthreads();
#pragma unroll
        for (int k = 0; k < 8; ++k) {
            float u = b2f(Us[k0 + k][row]);
            const ushort4* wr = (const ushort4*)(&Wt[k][grp * 32]);
#pragma unroll
            for (int j4 = 0; j4 < 8; ++j4) {
                ushort4 wv = wr[j4];
                acc[j4 * 4 + 0] += u * b2f(wv.x);
                acc[j4 * 4 + 1] += u * b2f(wv.y);
                acc[j4 * 4 + 2] += u * b2f(wv.z);
                acc[j4 * 4 + 3] += u * b2f(wv.w);
            }
        }
        __syncthreads();
    }

    const float scale = 0.04419417382415922f;
#pragma unroll
    for (int j = 0; j < 32; ++j) Qs[row][grp * 32 + j] = acc[j] * scale;
    if (t < 16) { mu_s[t] = -1e30f; ssum_s[t] = 0.f; }
#pragma unroll
    for (int j = 0; j < 32; ++j) acc[j] = 0.f;
    __syncthreads();

    const float4* qr = (const float4*)(&Qs[row][0]);

    for (int m0 = 0; m0 < Mm; m0 += 64) {
        {
            int mb = m0 + grp * 4;
            const uint4* K0 = (const uint4*)(Ktb + ((size_t)b * Mm + mb + 0) * Cd);
            const uint4* K1 = (const uint4*)(Ktb + ((size_t)b * Mm + mb + 1) * Cd);
            const uint4* K2 = (const uint4*)(Ktb + ((size_t)b * Mm + mb + 2) * Cd);
            const uint4* K3 = (const uint4*)(Ktb + ((size_t)b * Mm + mb + 3) * Cd);
            float a0 = 0.f, a1 = 0.f, a2 = 0.f, a3 = 0.f;
#pragma unroll 4
            for (int c8 = 0; c8 < Cd / 8; ++c8) {
                float4 qa = qr[2 * c8], qb = qr[2 * c8 + 1];
                uint4 k0v = K0[c8], k1v = K1[c8], k2v = K2[c8], k3v = K3[c8];
                a0 += qa.x * u2lo(k0v.x) + qa.y * u2hi(k0v.x) + qa.z * u2lo(k0v.y) + qa.w * u2hi(k0v.y)
                    + qb.x * u2lo(k0v.z) + qb.y * u2hi(k0v.z) + qb.z * u2lo(k0v.w) + qb.w * u2hi(k0v.w);
                a1 += qa.x * u2lo(k1v.x) + qa.y * u2hi(k1v.x) + qa.z * u2lo(k1v.y) + qa.w * u2hi(k1v.y)
                    + qb.x * u2lo(k1v.z) + qb.y * u2hi(k1v.z) + qb.z * u2lo(k1v.w) + qb.w * u2hi(k1v.w);
                a2 += qa.x * u2lo(k2v.x) + qa.y * u2hi(k2v.x) + qa.z * u2lo(k2v.y) + qa.w * u2hi(k2v.y)
                    + qb.x * u2lo(k2v.z) + qb.y * u2hi(k2v.z) + qb.z * u2lo(k2v.w) + qb.w * u2hi(k2v.w);
                a3 += qa.x * u2lo(k3v.x) + qa.y * u2hi(k3v.x) + qa.z * u2lo(k3v.y) + qa.w * u2hi(k3v.y)
                    + qb.x * u2lo(k3v.z) + qb.y * u2hi(k3v.z) + qb.z * u2lo(k3v.w) + qb.w * u2hi(k3v.w);
            }
            Ps[row][grp * 4 + 0] = a0;
            Ps[row][grp * 4 + 1] = a1;
            Ps[row][grp * 4 + 2] = a2;
            Ps[row][grp * 4 + 3] = a3;
        }
        __syncthreads();
        if (t < 16) {
            float mold = mu_s[t];
            float mx = mold;
            for (int m = 0; m < 64; ++m) mx = fmaxf(mx, Ps[t][m]);
            float al = __expf(mold - mx);
            float s = ssum_s[t] * al;
            for (int m = 0; m < 64; ++m) {
                float p = __expf(Ps[t][m] - mx);
                Ps[t][m] = p;
                s += p;
            }
            mu_s[t] = mx; ssum_s[t] = s; alpha_s[t] = al;
        }
        __syncthreads();
        {
            float arr = alpha_s[row];
#pragma unroll
            for (int j = 0; j < 32; ++j) acc[j] *= arr;
            const unsigned short* Vbase = Vtb + (size_t)b * Mm * Cd + (size_t)grp * 32;
            for (int m = 0; m < 64; ++m) {
                float p = Ps[row][m];
                const uint4* vr = (const uint4*)(Vbase + (size_t)(m0 + m) * Cd);
#pragma unroll
                for (int j4 = 0; j4 < 4; ++j4) {
                    uint4 v = vr[j4];
                    acc[j4 * 8 + 0] += p * u2lo(v.x); acc[j4 * 8 + 1] += p * u2hi(v.x);
                    acc[j4 * 8 + 2] += p * u2lo(v.y); acc[j4 * 8 + 3] += p * u2hi(v.y);
                    acc[j4 * 8 + 4] += p * u2lo(v.z); acc[j4 * 8 + 5] += p * u2hi(v.z);
                    acc[j4 * 8 + 6] += p * u2lo(v.w); acc[j4 * 8 + 7] += p * u2hi(v.w);
                }
            }
        }
        __syncthreads();
    }

    float invv = 1.0f / ssum_s[row];
#pragma unroll
    for (int j = 0; j < 32; ++j) {
        int c = grp * 32 + j;
        size_t idx = ((size_t)b * Cd + c) * Nn + n0 + row;
        out[idx] = out[idx] + acc[j] * invv;
    }
}

// ---------------------------------------------------------------------------
extern "C" void kernel_launch(void* const* d_in, const int* in_sizes, int n_in,
                              void* d_out, int out_size, void* d_ws, size_t ws_size,
                              hipStream_t stream) {
    const float* up   = (const float*)d_in[0];
    const float* down = (const float*)d_in[1];
    const float* Wq   = (const float*)d_in[2];
    const float* Wk   = (const float*)d_in[3];
    const float* Wv   = (const float*)d_in[4];
    const float* Wsk  = (const float*)d_in[5];
    float* out = (float*)d_out;

    const size_t szK = (size_t)Bn * Mm * Cd;   // bf16 elems: 4M (8 MiB)
    const size_t szQ = (size_t)Bn * Nn * Cd;   // bf16 elems: 16M (32 MiB)

    if (ws_size >= 2 * szK * 2 + szQ * 2) {
        // Fast path: Kt[m][c] | Vb[c][m] | Qt[n][c], all bf16. 48 MiB.
        unsigned short* Kt = (unsigned short*)d_ws;
        unsigned short* Vb = Kt + szK;
        unsigned short* Qt = Vb + szK;
        gemm_mfma<2><<<dim3(Mm / 64, Cd / 64, Bn), 256, 0, stream>>>(Wk, down, nullptr, Kt, Mm);
        gemm_mfma<1><<<dim3(Mm / 64, Cd / 64, Bn), 256, 0, stream>>>(Wv, down, nullptr, Vb, Mm);
        gemm_mfma<2><<<dim3(Nn / 64, Cd / 64, Bn), 256, 0, stream>>>(Wq, up, nullptr, Qt, Nn);
        gemm_mfma<0><<<dim3(Nn / 64, Cd / 64, Bn), 256, 0, stream>>>(Wsk, up, out, nullptr, Nn);
        attn_mfma<<<dim3(Nn / 32, Bn), 256, 0, stream>>>(Qt, Kt, Vb, out);
    } else {
        // Fallback (16 MiB ws): round-3 proven VALU attention.
        unsigned short* Ktb = (unsigned short*)d_ws;
        unsigned short* Vtb = Ktb + szK;
        gemm_mfma<2><<<dim3(Mm / 64, Cd / 64, Bn), 256, 0, stream>>>(Wk, down, nullptr, Ktb, Mm);
        gemm_mfma<2><<<dim3(Mm / 64, Cd / 64, Bn), 256, 0, stream>>>(Wv, down, nullptr, Vtb, Mm);
        gemm_mfma<0><<<dim3(Nn / 64, Cd / 64, Bn), 256, 0, stream>>>(Wsk, up, out, nullptr, Nn);
        attn_k<<<dim3(Nn / 16, Bn), 256, 0, stream>>>(up, Wq, Ktb, Vtb, out);
    }
}

// Round 5
// 598.212 us; speedup vs baseline: 5.5472x; 1.2200x over previous
//
#include <hip/hip_runtime.h>
#include <cstddef>

// Problem constants: B=8, C=512, N=4096, M=1024. Inputs f32, output f32.
#define Bn 8
#define Cd 512
#define Nn 4096
#define Mm 1024

typedef __attribute__((ext_vector_type(8))) short s8v;
typedef __attribute__((ext_vector_type(4))) float v4f;
typedef __attribute__((ext_vector_type(16))) float v16f;

__device__ __forceinline__ float b2f(unsigned short u) {
    union { unsigned int i; float f; } v; v.i = ((unsigned int)u) << 16; return v.f;
}
__device__ __forceinline__ unsigned short f2b(float f) {
    union { float f; unsigned int i; } v; v.f = f;
    unsigned int x = v.i;
    unsigned int r = (x + 0x7FFFu + ((x >> 16) & 1u)) >> 16;  // RNE
    return (unsigned short)r;
}
__device__ __forceinline__ v4f mfma16(s8v a, s8v b, v4f c) {
    return __builtin_amdgcn_mfma_f32_16x16x32_bf16(a, b, c, 0, 0, 0);
}
__device__ __forceinline__ v16f mfma32(s8v a, s8v b, v16f c) {
    return __builtin_amdgcn_mfma_f32_32x32x16_bf16(a, b, c, 0, 0, 0);
}

// ---------------------------------------------------------------------------
// MFMA GEMM (round-4 proven): D[o][n] = sum_c W[o][c] * X[c][n], per batch.
// MODE 0: f32  store D[o][n]   (skip -> out)
// MODE 1: bf16 store D[o][n]   (V -> Vb[c][m])
// MODE 2: bf16 store D^T[n][o] (Q -> Qt[n][c], K -> Kt[m][c])
// ---------------------------------------------------------------------------
template <int MODE>
__global__ __launch_bounds__(256) void gemm_mfma(const float* __restrict__ W,
                                                 const float* __restrict__ X,
                                                 float* __restrict__ Yf,
                                                 unsigned short* __restrict__ Yb,
                                                 int Nx) {
    __shared__ short Xs[64][40];
    __shared__ short Tt[16][72];
    const int t = threadIdx.x;
    const int w = t >> 6, lq = t & 15, quad = (t >> 4) & 3;
    const int b = blockIdx.z, o0 = blockIdx.y * 64, n0 = blockIdx.x * 64;
    const float* Xb = X + (size_t)b * Cd * Nx;
    const float* Wrow = W + (size_t)(o0 + w * 16 + lq) * Cd;

    v4f acc[4];
#pragma unroll
    for (int i = 0; i < 4; ++i) acc[i] = (v4f){0.f, 0.f, 0.f, 0.f};

    for (int c0 = 0; c0 < Cd; c0 += 32) {
#pragma unroll
        for (int p = 0; p < 2; ++p) {
            int i = t + p * 256;
            int c = i >> 4;
            int n4 = (i & 15) * 4;
            float4 x = *(const float4*)(Xb + (size_t)(c0 + c) * Nx + n0 + n4);
            Xs[n4 + 0][c] = (short)f2b(x.x); Xs[n4 + 1][c] = (short)f2b(x.y);
            Xs[n4 + 2][c] = (short)f2b(x.z); Xs[n4 + 3][c] = (short)f2b(x.w);
        }
        union { unsigned short h[8]; s8v s; } af;
        {
            float4 wa = *(const float4*)(Wrow + c0 + quad * 8);
            float4 wb = *(const float4*)(Wrow + c0 + quad * 8 + 4);
            af.h[0] = f2b(wa.x); af.h[1] = f2b(wa.y); af.h[2] = f2b(wa.z); af.h[3] = f2b(wa.w);
            af.h[4] = f2b(wb.x); af.h[5] = f2b(wb.y); af.h[6] = f2b(wb.z); af.h[7] = f2b(wb.w);
        }
        __syncthreads();
#pragma unroll
        for (int nt = 0; nt < 4; ++nt) {
            s8v bf = *(const s8v*)(&Xs[nt * 16 + lq][quad * 8]);
            acc[nt] = mfma16(af.s, bf, acc[nt]);
        }
        __syncthreads();
    }

    if (MODE == 0 || MODE == 1) {
#pragma unroll
        for (int nt = 0; nt < 4; ++nt)
#pragma unroll
            for (int r = 0; r < 4; ++r) {
                int o = o0 + w * 16 + quad * 4 + r;
                int n = n0 + nt * 16 + lq;
                size_t idx = ((size_t)b * Cd + o) * Nx + n;
                if (MODE == 0) Yf[idx] = acc[nt][r];
                else           Yb[idx] = f2b(acc[nt][r]);
            }
    } else {
#pragma unroll
        for (int nt = 0; nt < 4; ++nt) {
#pragma unroll
            for (int r = 0; r < 4; ++r)
                Tt[lq][w * 16 + quad * 4 + r] = (short)f2b(acc[nt][r]);
            __syncthreads();
            int nrow = t >> 4, o4 = (t & 15) * 4;
            ushort4 val = *(const ushort4*)(&Tt[nrow][o4]);
            *(ushort4*)(Yb + ((size_t)b * Nx + n0 + nt * 16 + nrow) * Cd + o0 + o4) = val;
            __syncthreads();
        }
    }
}

// ---------------------------------------------------------------------------
// attn_v2: flash attention, 32x32x16 MFMAs, K/V direct from global (L2),
// Q staged once in LDS (shared by 4 waves), P through LDS.
// Block = 256 thr / 4 waves handles (b, 32 q-rows). m-chunk = 128.
// QK^T computed as S^T = K x Q^T: wave w owns m-tile w (32 m); softmax over m
// is per-lane in-register (+1 shfl). PV: D[n][c] = P x V, wave w owns c-tiles
// {ti*128 + w*32}. Epilogue: out += O/l via LDS transpose, coalesced.
// Grid: 1024 linear; b = bid&7 (XCD affinity: batch's K+V (2MB) fits XCD L2).
// ---------------------------------------------------------------------------
__global__ __launch_bounds__(256, 2) void attn_v2(const unsigned short* __restrict__ Qt,
                                                  const unsigned short* __restrict__ Kt,
                                                  const unsigned short* __restrict__ Vb,
                                                  float* __restrict__ out) {
    __shared__ __align__(16) unsigned char Ls[42880];
    unsigned char* Lq = Ls;                                   // Qs: 32x512 bf16 swizzled (32768 B)
    unsigned short* Pb = (unsigned short*)(Ls + 32768);       // Pb[32][136] bf16 (8704 B)
    float* pmaxS  = (float*)(Ls + 41472);                     // [32][4]
    float* psumS  = (float*)(Ls + 41984);                     // [32][4]
    float* muS    = (float*)(Ls + 42496);                     // [32]
    float* ssumS  = (float*)(Ls + 42624);                     // [32]
    float* alphaS = (float*)(Ls + 42752);                     // [32]
    float* OtA    = (float*)Ls;                               // epilogue alias: [4][32][36] f32

    const int t = threadIdx.x;
    const int l = t & 63, w = t >> 6;
    const int lcol = l & 31, lhalf = l >> 5;
    const int bid = blockIdx.x;
    const int b = bid & 7, n0 = (bid >> 3) * 32;

    // ---- stage Q (32 rows x 512 c, bf16) swizzled: unit u of row n at u^(n&15)
    {
        const unsigned short* qb = Qt + ((size_t)b * Nn + n0) * Cd;
#pragma unroll
        for (int i = 0; i < 8; ++i) {
            int s = i * 256 + t;           // unit id 0..2047
            int n = s >> 6, u = s & 63;
            uint4 v = *(const uint4*)(qb + (size_t)n * Cd + u * 8);
            *(uint4*)(Lq + ((n * 64 + (u ^ (n & 15))) << 4)) = v;
        }
    }
    if (t < 32) { muS[t] = -1e30f; ssumS[t] = 0.f; }

    v16f o_acc[4];
#pragma unroll
    for (int i = 0; i < 4; ++i)
#pragma unroll
        for (int r = 0; r < 16; ++r) o_acc[i][r] = 0.f;
    __syncthreads();

    const unsigned short* Kp = Kt + ((size_t)b * Mm + w * 32 + lcol) * Cd + lhalf * 8;
    const unsigned short* Vp = Vb + (size_t)b * Cd * Mm + lhalf * 8;
    const int qrow = lcol * 64;     // Q LDS unit base for col n=lcol
    const int swz = lcol & 15;
    const float sc = 0.04419417382415922f;   // 1/sqrt(512)

    for (int m0 = 0; m0 < Mm; m0 += 128) {
        // ---- QK^T: S^T[m = w*32 + regmap][n = lcol], K from global, Q from LDS
        v16f st;
#pragma unroll
        for (int r = 0; r < 16; ++r) st[r] = 0.f;
        const unsigned short* kp = Kp + (size_t)m0 * Cd;
#pragma unroll
        for (int kb8 = 0; kb8 < 4; ++kb8) {
            uint4 ka[8];
#pragma unroll
            for (int j = 0; j < 8; ++j) ka[j] = *(const uint4*)(kp + (kb8 * 8 + j) * 16);
#pragma unroll
            for (int j = 0; j < 8; ++j) {
                int kb = kb8 * 8 + j;
                s8v qf = *(const s8v*)(Lq + ((qrow + ((kb * 2 + lhalf) ^ swz)) << 4));
                union { uint4 u; s8v s; } av; av.u = ka[j];
                st = mfma32(av.s, qf, st);
            }
        }
        // ---- softmax bookkeeping (per-lane over 16 regs = 16 of 32 m) ----
#pragma unroll
        for (int r = 0; r < 16; ++r) st[r] *= sc;
        float tm = st[0];
#pragma unroll
        for (int r = 1; r < 16; ++r) tm = fmaxf(tm, st[r]);
        tm = fmaxf(tm, __shfl_xor(tm, 32));
        if (l < 32) pmaxS[l * 4 + w] = tm;
        __syncthreads();   // S1
        if (t < 32) {
            float mx = muS[t];
            mx = fmaxf(mx, fmaxf(fmaxf(pmaxS[t * 4], pmaxS[t * 4 + 1]),
                                 fmaxf(pmaxS[t * 4 + 2], pmaxS[t * 4 + 3])));
            alphaS[t] = __expf(muS[t] - mx);
            muS[t] = mx;
        }
        __syncthreads();   // S2
        {
            float mxn = muS[lcol];
            float e[16], rs = 0.f;
#pragma unroll
            for (int r = 0; r < 16; ++r) { e[r] = __expf(st[r] - mxn); rs += e[r]; }
            rs += __shfl_xor(rs, 32);
            if (l < 32) psumS[l * 4 + w] = rs;
#pragma unroll
            for (int rg = 0; rg < 4; ++rg) {
                ushort4 pk;
                pk.x = f2b(e[rg * 4 + 0]); pk.y = f2b(e[rg * 4 + 1]);
                pk.z = f2b(e[rg * 4 + 2]); pk.w = f2b(e[rg * 4 + 3]);
                *(ushort4*)(Pb + lcol * 136 + w * 32 + 8 * rg + 4 * lhalf) = pk;
            }
        }
        __syncthreads();   // S3
        if (t < 32)
            ssumS[t] = ssumS[t] * alphaS[t] +
                       psumS[t * 4] + psumS[t * 4 + 1] + psumS[t * 4 + 2] + psumS[t * 4 + 3];

        // ---- PV: D[n = regmap][c = lcol], P from LDS (reg-cached), V global ----
        float ar[16];
#pragma unroll
        for (int r = 0; r < 16; ++r)
            ar[r] = alphaS[(r & 3) + 8 * (r >> 2) + 4 * lhalf];
#pragma unroll
        for (int ti = 0; ti < 4; ++ti)
#pragma unroll
            for (int r = 0; r < 16; ++r) o_acc[ti][r] *= ar[r];

        s8v pA[8];
#pragma unroll
        for (int kb = 0; kb < 8; ++kb)
            pA[kb] = *(const s8v*)(Pb + lcol * 136 + kb * 16 + lhalf * 8);

#pragma unroll
        for (int ti = 0; ti < 4; ++ti) {
            int c = ti * 128 + w * 32 + lcol;
            const unsigned short* vc = Vp + (size_t)c * Mm + m0;
            uint4 vb8[8];
#pragma unroll
            for (int kb = 0; kb < 8; ++kb) vb8[kb] = *(const uint4*)(vc + kb * 16);
#pragma unroll
            for (int kb = 0; kb < 8; ++kb) {
                union { uint4 u; s8v s; } bv; bv.u = vb8[kb];
                o_acc[ti] = mfma32(pA[kb], bv.s, o_acc[ti]);
            }
        }
        __syncthreads();   // protect Pb/pmax/psum for next chunk
    }

    // ---- epilogue: out[b][c][n0..n0+31] += O / l ----
    float inv[16];
#pragma unroll
    for (int r = 0; r < 16; ++r)
        inv[r] = 1.0f / ssumS[(r & 3) + 8 * (r >> 2) + 4 * lhalf];

    float* OtW = OtA + w * 32 * 36;
#pragma unroll
    for (int ti = 0; ti < 4; ++ti) {
#pragma unroll
        for (int r = 0; r < 16; ++r)
            OtW[lcol * 36 + (r & 3) + 8 * (r >> 2) + 4 * lhalf] = o_acc[ti][r] * inv[r];
        __syncthreads();
        {
            int cloc = l >> 1, half = l & 1;
            int cabs = ti * 128 + w * 32 + cloc;
            const float* src = OtW + cloc * 36 + half * 16;
            float* op = out + ((size_t)b * Cd + cabs) * Nn + n0 + half * 16;
#pragma unroll
            for (int j = 0; j < 4; ++j) {
                float4 a = *(const float4*)(src + j * 4);
                float4 g = *(const float4*)(op + j * 4);
                g.x += a.x; g.y += a.y; g.z += a.z; g.w += a.w;
                *(float4*)(op + j * 4) = g;
            }
        }
        __syncthreads();
    }
}

// ---------------------------------------------------------------------------
// Fallback VALU attention (round-3 proven) for small ws_size.
// ---------------------------------------------------------------------------
__device__ __forceinline__ float u2lo(unsigned int u) {
    union { unsigned int i; float f; } v; v.i = u << 16; return v.f;
}
__device__ __forceinline__ float u2hi(unsigned int u) {
    union { unsigned int i; float f; } v; v.i = u & 0xFFFF0000u; return v.f;
}

__global__ __launch_bounds__(256) void attn_k(const float* __restrict__ up,
                                              const float* __restrict__ Wq,
                                              const unsigned short* __restrict__ Ktb,
                                              const unsigned short* __restrict__ Vtb,
                                              float* __restrict__ out) {
    __shared__ float Qs[16][516];
    __shared__ __align__(16) unsigned char Sraw[24576];
    unsigned short (*Us)[16]  = reinterpret_cast<unsigned short(*)[16]>(Sraw);
    unsigned short (*Wt)[512] = reinterpret_cast<unsigned short(*)[512]>(Sraw + 16384);
    float (*Ps)[65] = reinterpret_cast<float(*)[65]>(Sraw);
    float* mu_s     = reinterpret_cast<float*>(Sraw + 4160);
    float* ssum_s   = reinterpret_cast<float*>(Sraw + 4224);
    float* alpha_s  = reinterpret_cast<float*>(Sraw + 4288);

    const int t = threadIdx.x;
    const int b = blockIdx.y;
    const int n0 = blockIdx.x * 16;
    const int row = t & 15;
    const int grp = t >> 4;

    for (int i = t; i < Cd * 16; i += 256) {
        int c = i >> 4, r = i & 15;
        Us[c][r] = f2b(up[((size_t)b * Cd + c) * Nn + n0 + r]);
    }
    __syncthreads();

    float acc[32];
#pragma unroll
    for (int j = 0; j < 32; ++j) acc[j] = 0.f;

    for (int k0 = 0; k0 < Cd; k0 += 8) {
        for (int i = t; i < 1024; i += 256) {
            int oc = i >> 1;
            int kc = (i & 1) * 4;
            float4 wv = *(const float4*)(Wq + (size_t)oc * Cd + k0 + kc);
            Wt[kc + 0][oc] = f2b(wv.x); Wt[kc + 1][oc] = f2b(wv.y);
            Wt[kc + 2][oc] = f2b(wv.z); Wt[kc + 3][oc] = f2b(wv.w);
        }
        __syncthreads();
#pragma unroll
        for (int k = 0; k < 8; ++k) {
            float u = b2f(Us[k0 + k][row]);
            const ushort4* wr = (const ushort4*)(&Wt[k][grp * 32]);
#pragma unroll
            for (int j4 = 0; j4 < 8; ++j4) {
                ushort4 wv = wr[j4];
                acc[j4 * 4 + 0] += u * b2f(wv.x);
                acc[j4 * 4 + 1] += u * b2f(wv.y);
                acc[j4 * 4 + 2] += u * b2f(wv.z);
                acc[j4 * 4 + 3] += u * b2f(wv.w);
            }
        }
        __syncthreads();
    }

    const float scale = 0.04419417382415922f;
#pragma unroll
    for (int j = 0; j < 32; ++j) Qs[row][grp * 32 + j] = acc[j] * scale;
    if (t < 16) { mu_s[t] = -1e30f; ssum_s[t] = 0.f; }
#pragma unroll
    for (int j = 0; j < 32; ++j) acc[j] = 0.f;
    __syncthreads();

    const float4* qr = (const float4*)(&Qs[row][0]);

    for (int m0 = 0; m0 < Mm; m0 += 64) {
        {
            int mb = m0 + grp * 4;
            const uint4* K0 = (const uint4*)(Ktb + ((size_t)b * Mm + mb + 0) * Cd);
            const uint4* K1 = (const uint4*)(Ktb + ((size_t)b * Mm + mb + 1) * Cd);
            const uint4* K2 = (const uint4*)(Ktb + ((size_t)b * Mm + mb + 2) * Cd);
            const uint4* K3 = (const uint4*)(Ktb + ((size_t)b * Mm + mb + 3) * Cd);
            float a0 = 0.f, a1 = 0.f, a2 = 0.f, a3 = 0.f;
#pragma unroll 4
            for (int c8 = 0; c8 < Cd / 8; ++c8) {
                float4 qa = qr[2 * c8], qb = qr[2 * c8 + 1];
                uint4 k0v = K0[c8], k1v = K1[c8], k2v = K2[c8], k3v = K3[c8];
                a0 += qa.x * u2lo(k0v.x) + qa.y * u2hi(k0v.x) + qa.z * u2lo(k0v.y) + qa.w * u2hi(k0v.y)
                    + qb.x * u2lo(k0v.z) + qb.y * u2hi(k0v.z) + qb.z * u2lo(k0v.w) + qb.w * u2hi(k0v.w);
                a1 += qa.x * u2lo(k1v.x) + qa.y * u2hi(k1v.x) + qa.z * u2lo(k1v.y) + qa.w * u2hi(k1v.y)
                    + qb.x * u2lo(k1v.z) + qb.y * u2hi(k1v.z) + qb.z * u2lo(k1v.w) + qb.w * u2hi(k1v.w);
                a2 += qa.x * u2lo(k2v.x) + qa.y * u2hi(k2v.x) + qa.z * u2lo(k2v.y) + qa.w * u2hi(k2v.y)
                    + qb.x * u2lo(k2v.z) + qb.y * u2hi(k2v.z) + qb.z * u2lo(k2v.w) + qb.w * u2hi(k2v.w);
                a3 += qa.x * u2lo(k3v.x) + qa.y * u2hi(k3v.x) + qa.z * u2lo(k3v.y) + qa.w * u2hi(k3v.y)
                    + qb.x * u2lo(k3v.z) + qb.y * u2hi(k3v.z) + qb.z * u2lo(k3v.w) + qb.w * u2hi(k3v.w);
            }
            Ps[row][grp * 4 + 0] = a0;
            Ps[row][grp * 4 + 1] = a1;
            Ps[row][grp * 4 + 2] = a2;
            Ps[row][grp * 4 + 3] = a3;
        }
        __syncthreads();
        if (t < 16) {
            float mold = mu_s[t];
            float mx = mold;
            for (int m = 0; m < 64; ++m) mx = fmaxf(mx, Ps[t][m]);
            float al = __expf(mold - mx);
            float s = ssum_s[t] * al;
            for (int m = 0; m < 64; ++m) {
                float p = __expf(Ps[t][m] - mx);
                Ps[t][m] = p;
                s += p;
            }
            mu_s[t] = mx; ssum_s[t] = s; alpha_s[t] = al;
        }
        __syncthreads();
        {
            float arr = alpha_s[row];
#pragma unroll
            for (int j = 0; j < 32; ++j) acc[j] *= arr;
            const unsigned short* Vbase = Vtb + (size_t)b * Mm * Cd + (size_t)grp * 32;
            for (int m = 0; m < 64; ++m) {
                float p = Ps[row][m];
                const uint4* vr = (const uint4*)(Vbase + (size_t)(m0 + m) * Cd);
#pragma unroll
                for (int j4 = 0; j4 < 4; ++j4) {
                    uint4 v = vr[j4];
                    acc[j4 * 8 + 0] += p * u2lo(v.x); acc[j4 * 8 + 1] += p * u2hi(v.x);
                    acc[j4 * 8 + 2] += p * u2lo(v.y); acc[j4 * 8 + 3] += p * u2hi(v.y);
                    acc[j4 * 8 + 4] += p * u2lo(v.z); acc[j4 * 8 + 5] += p * u2hi(v.z);
                    acc[j4 * 8 + 6] += p * u2lo(v.w); acc[j4 * 8 + 7] += p * u2hi(v.w);
                }
            }
        }
        __syncthreads();
    }

    float invv = 1.0f / ssum_s[row];
#pragma unroll
    for (int j = 0; j < 32; ++j) {
        int c = grp * 32 + j;
        size_t idx = ((size_t)b * Cd + c) * Nn + n0 + row;
        out[idx] = out[idx] + acc[j] * invv;
    }
}

// ---------------------------------------------------------------------------
extern "C" void kernel_launch(void* const* d_in, const int* in_sizes, int n_in,
                              void* d_out, int out_size, void* d_ws, size_t ws_size,
                              hipStream_t stream) {
    const float* up   = (const float*)d_in[0];
    const float* down = (const float*)d_in[1];
    const float* Wq   = (const float*)d_in[2];
    const float* Wk   = (const float*)d_in[3];
    const float* Wv   = (const float*)d_in[4];
    const float* Wsk  = (const float*)d_in[5];
    float* out = (float*)d_out;

    const size_t szK = (size_t)Bn * Mm * Cd;   // bf16 elems: 4M (8 MiB)
    const size_t szQ = (size_t)Bn * Nn * Cd;   // bf16 elems: 16M (32 MiB)

    if (ws_size >= 2 * szK * 2 + szQ * 2) {
        // Fast path: Kt[m][c] | Vb[c][m] | Qt[n][c], all bf16. 48 MiB.
        unsigned short* Kt = (unsigned short*)d_ws;
        unsigned short* Vb = Kt + szK;
        unsigned short* Qt = Vb + szK;
        gemm_mfma<2><<<dim3(Mm / 64, Cd / 64, Bn), 256, 0, stream>>>(Wk, down, nullptr, Kt, Mm);
        gemm_mfma<1><<<dim3(Mm / 64, Cd / 64, Bn), 256, 0, stream>>>(Wv, down, nullptr, Vb, Mm);
        gemm_mfma<2><<<dim3(Nn / 64, Cd / 64, Bn), 256, 0, stream>>>(Wq, up, nullptr, Qt, Nn);
        gemm_mfma<0><<<dim3(Nn / 64, Cd / 64, Bn), 256, 0, stream>>>(Wsk, up, out, nullptr, Nn);
        attn_v2<<<dim3((Nn / 32) * Bn), 256, 0, stream>>>(Qt, Kt, Vb, out);
    } else {
        // Fallback (16 MiB ws): round-3 proven VALU attention.
        unsigned short* Ktb = (unsigned short*)d_ws;
        unsigned short* Vtb = Ktb + szK;
        gemm_mfma<2><<<dim3(Mm / 64, Cd / 64, Bn), 256, 0, stream>>>(Wk, down, nullptr, Ktb, Mm);
        gemm_mfma<2><<<dim3(Mm / 64, Cd / 64, Bn), 256, 0, stream>>>(Wv, down, nullptr, Vtb, Mm);
        gemm_mfma<0><<<dim3(Nn / 64, Cd / 64, Bn), 256, 0, stream>>>(Wsk, up, out, nullptr, Nn);
        attn_k<<<dim3(Nn / 16, Bn), 256, 0, stream>>>(up, Wq, Ktb, Vtb, out);
    }
}